// Round 1
// baseline (12355.415 us; speedup 1.0000x reference)
//
#include <hip/hip_runtime.h>
#include <cmath>

#define SS 512
#define BB 32
#define EE 128
#define HH 256
#define VV 10000
#define NROWS (SS*BB)   // 16384

__device__ __forceinline__ float sigmoidf_(float x) { return 1.0f / (1.0f + expf(-x)); }

// Z[m][0:1024] = bias + A[m][0:Kx] @ Wk[0:Kx][0:1024]
// A gathered from embedding (idx != null, Kx=128) or read from prev-layer out (Kx=256).
// Row m = t*BB + b. 16 rows per block, 256 threads, 4 cols (float4) per thread.
__global__ __launch_bounds__(256)
void zgemm_kernel(const float* __restrict__ Wk, const float* __restrict__ bias,
                  const float* __restrict__ xin, const int* __restrict__ idx,
                  float* __restrict__ Z, int Kx)
{
    __shared__ float A[16][256];
    const int tid = threadIdx.x;
    const int m0 = blockIdx.x * 16;
    if (idx) {
        for (int i = tid; i < 16 * EE; i += 256) {
            const int r = i >> 7, cc = i & (EE - 1);
            const int m = m0 + r;
            const int t = m >> 5, b = m & (BB - 1);
            const int id = idx[b * SS + t];
            A[r][cc] = xin[(size_t)id * EE + cc];
        }
    } else {
        for (int i = tid; i < 16 * HH; i += 256) {
            const int r = i >> 8, cc = i & (HH - 1);
            A[r][cc] = xin[(size_t)(m0 + r) * HH + cc];
        }
    }
    __syncthreads();
    const float4 b4 = ((const float4*)bias)[tid];
    float4 acc[16];
#pragma unroll
    for (int i = 0; i < 16; i++) acc[i] = b4;
    for (int r = 0; r < Kx; r++) {
        const float4 w = ((const float4*)(Wk + (size_t)r * 1024))[tid];
#pragma unroll
        for (int i = 0; i < 16; i++) {
            const float a = A[i][r];
            acc[i].x += a * w.x; acc[i].y += a * w.y;
            acc[i].z += a * w.z; acc[i].w += a * w.w;
        }
    }
#pragma unroll
    for (int i = 0; i < 16; i++)
        ((float4*)(Z + (size_t)(m0 + i) * 1024))[tid] = acc[i];
}

// One workgroup per batch element; thread j owns hidden unit j and gate
// columns 4j..4j+3 during the matmul (float4 weight loads), then reads its
// unit's i/g/f/o from the z scratch in LDS. TF LSTMCell: i,g,f,o; forget_bias=1.
__global__ __launch_bounds__(256)
void lstm_kernel(const float* __restrict__ Wk, const float* __restrict__ bias,
                 const int* __restrict__ lens, const int* __restrict__ idx,
                 const float* __restrict__ xin, const float* __restrict__ Z,
                 float* __restrict__ outp, int Kx)
{
    __shared__ float hsh[HH];
    __shared__ float xsh[HH];
    __shared__ float zsh[4 * HH];
    const int j = threadIdx.x;
    const int b = blockIdx.x;
    const int len = lens[b];
    float c = 0.f, hprev = 0.f;
    hsh[j] = 0.f;
    const float4 b4 = ((const float4*)bias)[j];
    const float* Wh = Wk + (size_t)Kx * 1024;
    __syncthreads();
    for (int t = 0; t < SS; t++) {
        float4 acc;
        if (Z) {
            acc = ((const float4*)(Z + (size_t)(t * BB + b) * 1024))[j];
            __syncthreads();                    // B0: hsh write(t-1) -> reads below
        } else {
            __syncthreads();                    // B0: protect hsh/xsh overwrite
            if (idx) { if (j < Kx) xsh[j] = xin[(size_t)idx[b * SS + t] * EE + j]; }
            else     { xsh[j] = xin[(size_t)(t * BB + b) * HH + j]; }
            acc = b4;
            __syncthreads();                    // xsh ready
            for (int r = 0; r < Kx; r++) {
                const float4 w = ((const float4*)(Wk + (size_t)r * 1024))[j];
                const float a = xsh[r];
                acc.x += a * w.x; acc.y += a * w.y; acc.z += a * w.z; acc.w += a * w.w;
            }
        }
        for (int r = 0; r < HH; r++) {
            const float4 w = ((const float4*)(Wh + (size_t)r * 1024))[j];
            const float a = hsh[r];
            acc.x += a * w.x; acc.y += a * w.y; acc.z += a * w.z; acc.w += a * w.w;
        }
        ((float4*)zsh)[j] = acc;
        __syncthreads();                        // B1: zsh complete, hsh reads done
        const float zi = zsh[j], zg = zsh[HH + j], zf = zsh[2 * HH + j], zo = zsh[3 * HH + j];
        const float ig = sigmoidf_(zi);
        const float gg = tanhf(zg);
        const float fg = sigmoidf_(zf + 1.0f);
        const float og = sigmoidf_(zo);
        const float cn = fg * c + ig * gg;
        const float hn = og * tanhf(cn);
        const bool act = (t < len);
        c = act ? cn : c;
        const float ho = act ? hn : hprev;
        hprev = ho;
        outp[(size_t)(t * BB + b) * HH + j] = act ? hn : 0.f;
        hsh[j] = ho;                            // visible after next B0
    }
}

// Fused projection + log-softmax CE, flash-style over V.
// Block: 64 rows; 256 threads = 16 col-threads (tx) x 16 row-groups (ty), each
// thread 4 rows x 4 cols per 64-col chunk. Online (max, sumexp) per row.
__global__ __launch_bounds__(256)
void ce_kernel(const float* __restrict__ h2, const float* __restrict__ W,
               const float* __restrict__ ob, const int* __restrict__ y,
               const int* __restrict__ lens, float* __restrict__ out)
{
    __shared__ float sh[64][257];
    __shared__ float red[16];
    const int tid = threadIdx.x;
    const int tx = tid & 15, ty = tid >> 4;
    const int m0 = blockIdx.x * 64;
    for (int i = tid; i < 64 * 64; i += 256) {
        const int r = i >> 6, c4 = i & 63;
        const float4 v = ((const float4*)(h2 + (size_t)(m0 + r) * HH))[c4];
        sh[r][c4 * 4 + 0] = v.x; sh[r][c4 * 4 + 1] = v.y;
        sh[r][c4 * 4 + 2] = v.z; sh[r][c4 * 4 + 3] = v.w;
    }
    __syncthreads();
    float mrun[4], lrun[4], tgt[4];
    int yv[4], bi[4];
#pragma unroll
    for (int i = 0; i < 4; i++) {
        const int m = m0 + ty * 4 + i;
        const int s = m >> 5, b = m & (BB - 1);
        yv[i] = y[b * SS + s];
        bi[i] = b;
        mrun[i] = -INFINITY; lrun[i] = 0.f; tgt[i] = 0.f;
    }
    for (int c0 = 0; c0 < VV; c0 += 64) {
        const int cc = c0 + tx * 4;
        float4 acc[4];
#pragma unroll
        for (int i = 0; i < 4; i++) acc[i] = make_float4(0.f, 0.f, 0.f, 0.f);
        if (c0 + 64 <= VV) {
            for (int k = 0; k < HH; k++) {
                const float4 w = *(const float4*)(W + (size_t)k * VV + cc);
#pragma unroll
                for (int i = 0; i < 4; i++) {
                    const float a = sh[ty * 4 + i][k];
                    acc[i].x += a * w.x; acc[i].y += a * w.y;
                    acc[i].z += a * w.z; acc[i].w += a * w.w;
                }
            }
        } else {
            for (int k = 0; k < HH; k++) {
                float4 w;
                w.x = (cc + 0 < VV) ? W[(size_t)k * VV + cc + 0] : 0.f;
                w.y = (cc + 1 < VV) ? W[(size_t)k * VV + cc + 1] : 0.f;
                w.z = (cc + 2 < VV) ? W[(size_t)k * VV + cc + 2] : 0.f;
                w.w = (cc + 3 < VV) ? W[(size_t)k * VV + cc + 3] : 0.f;
#pragma unroll
                for (int i = 0; i < 4; i++) {
                    const float a = sh[ty * 4 + i][k];
                    acc[i].x += a * w.x; acc[i].y += a * w.y;
                    acc[i].z += a * w.z; acc[i].w += a * w.w;
                }
            }
        }
        float ob4[4];
#pragma unroll
        for (int jj = 0; jj < 4; jj++) ob4[jj] = (cc + jj < VV) ? ob[cc + jj] : 0.f;
#pragma unroll
        for (int i = 0; i < 4; i++) {
            float sc[4] = { acc[i].x + ob4[0], acc[i].y + ob4[1],
                            acc[i].z + ob4[2], acc[i].w + ob4[3] };
#pragma unroll
            for (int jj = 0; jj < 4; jj++) if (cc + jj >= VV) sc[jj] = -INFINITY;
            float cm = fmaxf(fmaxf(sc[0], sc[1]), fmaxf(sc[2], sc[3]));
            for (int off = 1; off < 16; off <<= 1) cm = fmaxf(cm, __shfl_xor(cm, off, 16));
            const float newm = fmaxf(mrun[i], cm);
            float ssum = 0.f;
#pragma unroll
            for (int jj = 0; jj < 4; jj++) ssum += expf(sc[jj] - newm);
            for (int off = 1; off < 16; off <<= 1) ssum += __shfl_xor(ssum, off, 16);
            lrun[i] = lrun[i] * expf(mrun[i] - newm) + ssum;
            mrun[i] = newm;
#pragma unroll
            for (int jj = 0; jj < 4; jj++) if (cc + jj == yv[i]) tgt[i] += sc[jj];
        }
    }
    float local = 0.f;
#pragma unroll
    for (int i = 0; i < 4; i++) {
        for (int off = 1; off < 16; off <<= 1) tgt[i] += __shfl_xor(tgt[i], off, 16);
        const float lse = mrun[i] + logf(lrun[i]);
        const float xe = lse - tgt[i];
        if (yv[i] != 0) local += xe / (32.0f * (float)lens[bi[i]]);
    }
    if (tx == 0) red[ty] = local;
    __syncthreads();
    if (tid == 0) {
        float s = 0.f;
        for (int i = 0; i < 16; i++) s += red[i];
        atomicAdd(out, s);
    }
}

extern "C" void kernel_launch(void* const* d_in, const int* in_sizes, int n_in,
                              void* d_out, int out_size, void* d_ws, size_t ws_size,
                              hipStream_t stream)
{
    const int*   input_x = (const int*)  d_in[0];
    const int*   input_y = (const int*)  d_in[1];
    const int*   lens    = (const int*)  d_in[2];
    const float* emb_W   = (const float*)d_in[3];
    const float* k0      = (const float*)d_in[4];
    const float* b0      = (const float*)d_in[5];
    const float* k1      = (const float*)d_in[6];
    const float* b1      = (const float*)d_in[7];
    const float* out_W   = (const float*)d_in[8];
    const float* out_b   = (const float*)d_in[9];
    float* out = (float*)d_out;

    const size_t zbytes = (size_t)NROWS * 1024 * sizeof(float); // 64 MB
    const size_t hbytes = (size_t)NROWS * HH * sizeof(float);   // 16 MB
    const bool useZ = (ws_size >= zbytes + 2 * hbytes);         // 96 MB total

    float* Z  = (float*)d_ws;
    float* h1 = useZ ? (float*)((char*)d_ws + zbytes) : (float*)d_ws;
    float* h2 = (float*)((char*)h1 + hbytes);

    hipMemsetAsync(d_out, 0, sizeof(float), stream);

    if (useZ) {
        zgemm_kernel<<<NROWS / 16, 256, 0, stream>>>(k0, b0, emb_W, input_x, Z, EE);
        lstm_kernel <<<BB, 256, 0, stream>>>(k0, b0, lens, nullptr, nullptr, Z, h1, EE);
        zgemm_kernel<<<NROWS / 16, 256, 0, stream>>>(k1, b1, h1, nullptr, Z, HH);
        lstm_kernel <<<BB, 256, 0, stream>>>(k1, b1, lens, nullptr, nullptr, Z, h2, HH);
    } else {
        lstm_kernel <<<BB, 256, 0, stream>>>(k0, b0, lens, input_x, emb_W, nullptr, h1, EE);
        lstm_kernel <<<BB, 256, 0, stream>>>(k1, b1, lens, nullptr, h1, nullptr, h2, HH);
    }
    ce_kernel<<<NROWS / 64, 256, 0, stream>>>(h2, out_W, out_b, input_y, lens, out);
}

// Round 2
// 10932.860 us; speedup vs baseline: 1.1301x; 1.1301x over previous
//
#include <hip/hip_runtime.h>
#include <cmath>

#define SS 512
#define BB 32
#define EE 128
#define HH 256
#define VV 10000
#define NROWS (SS*BB)   // 16384
#define NC 2            // V-chunks in ce
#define CCHUNK 5056     // 79*64; chunk1 = 4944

__device__ __forceinline__ float sigmoidf_(float x) { return 1.0f / (1.0f + expf(-x)); }

// Z[m][0:1024] = bias + A[m][0:Kx] @ Wk[0:Kx][0:1024]
__global__ __launch_bounds__(256)
void zgemm_kernel(const float* __restrict__ Wk, const float* __restrict__ bias,
                  const float* __restrict__ xin, const int* __restrict__ idx,
                  float* __restrict__ Z, int Kx)
{
    __shared__ float A[16][256];
    const int tid = threadIdx.x;
    const int m0 = blockIdx.x * 16;
    if (idx) {
        for (int i = tid; i < 16 * EE; i += 256) {
            const int r = i >> 7, cc = i & (EE - 1);
            const int m = m0 + r;
            const int t = m >> 5, b = m & (BB - 1);
            const int id = idx[b * SS + t];
            A[r][cc] = xin[(size_t)id * EE + cc];
        }
    } else {
        for (int i = tid; i < 16 * HH; i += 256) {
            const int r = i >> 8, cc = i & (HH - 1);
            A[r][cc] = xin[(size_t)(m0 + r) * HH + cc];
        }
    }
    __syncthreads();
    const float4 b4 = ((const float4*)bias)[tid];
    float4 acc[16];
#pragma unroll
    for (int i = 0; i < 16; i++) acc[i] = b4;
    for (int r = 0; r < Kx; r++) {
        const float4 w = ((const float4*)(Wk + (size_t)r * 1024))[tid];
#pragma unroll
        for (int i = 0; i < 16; i++) {
            const float a = A[i][r];
            acc[i].x += a * w.x; acc[i].y += a * w.y;
            acc[i].z += a * w.z; acc[i].w += a * w.w;
        }
    }
#pragma unroll
    for (int i = 0; i < 16; i++)
        ((float4*)(Z + (size_t)(m0 + i) * 1024))[tid] = acc[i];
}

// One WG (1024 threads = 16 waves = 4 waves/SIMD) per batch element.
// tid = kq*256 + j: thread computes partial of gate cols 4j..4j+3 over
// h-rows [kq*64, kq*64+64); LDS tree-reduce; threads 0..255 do gate math.
__global__ __launch_bounds__(1024)
void lstm_kernel(const float* __restrict__ Wk, const float* __restrict__ bias,
                 const int* __restrict__ lens, const int* __restrict__ idx,
                 const float* __restrict__ xin, const float* __restrict__ Z,
                 float* __restrict__ outp, int Kx)
{
    __shared__ float hsh[HH];
    __shared__ float xsh[HH];
    __shared__ float psum[4][1024];
    const int tid = threadIdx.x;
    const int j = tid & 255;
    const int kq = tid >> 8;
    const int b = blockIdx.x;
    const int len = lens[b];
    float c = 0.f, hprev = 0.f;
    if (tid < HH) hsh[tid] = 0.f;
    const float4 b4 = ((const float4*)bias)[j];
    const float* Wh = Wk + (size_t)Kx * 1024;
    const int r0 = kq * 64;          // h-row slice start
    const int xK = Kx >> 2;          // x-row slice size
    const int xr0 = kq * xK;
    __syncthreads();

    float4 zr = make_float4(0.f, 0.f, 0.f, 0.f);
    if (Z && kq == 0) zr = ((const float4*)(Z + (size_t)(0 * BB + b) * 1024))[j];

    for (int t = 0; t < SS; t++) {
        float4 acc;
        if (Z) {
            acc = (kq == 0) ? zr : make_float4(0.f, 0.f, 0.f, 0.f);
            __syncthreads();                    // A: hsh(t-1) written, psum reads done
        } else {
            __syncthreads();                    // A
            if (idx) { if (tid < Kx) xsh[tid] = xin[(size_t)idx[b * SS + t] * EE + tid]; }
            else     { if (tid < HH) xsh[tid] = xin[(size_t)(t * BB + b) * HH + tid]; }
            acc = (kq == 0) ? b4 : make_float4(0.f, 0.f, 0.f, 0.f);
            __syncthreads();                    // xsh ready
#pragma unroll 4
            for (int rr = 0; rr < xK; rr++) {
                const int r = xr0 + rr;
                const float4 w = ((const float4*)(Wk + (size_t)r * 1024))[j];
                const float a = xsh[r];
                acc.x += a * w.x; acc.y += a * w.y; acc.z += a * w.z; acc.w += a * w.w;
            }
        }
        // h-part: 16 float4 reads of hsh, 64 weight rows
        const float4* hsh4 = (const float4*)hsh;
#pragma unroll 4
        for (int rr4 = 0; rr4 < 16; rr4++) {
            const float4 a4 = hsh4[(kq << 4) + rr4];
            const int r = r0 + rr4 * 4;
            {
                const float4 w = ((const float4*)(Wh + (size_t)(r + 0) * 1024))[j];
                acc.x += a4.x * w.x; acc.y += a4.x * w.y; acc.z += a4.x * w.z; acc.w += a4.x * w.w;
            }
            {
                const float4 w = ((const float4*)(Wh + (size_t)(r + 1) * 1024))[j];
                acc.x += a4.y * w.x; acc.y += a4.y * w.y; acc.z += a4.y * w.z; acc.w += a4.y * w.w;
            }
            {
                const float4 w = ((const float4*)(Wh + (size_t)(r + 2) * 1024))[j];
                acc.x += a4.z * w.x; acc.y += a4.z * w.y; acc.z += a4.z * w.z; acc.w += a4.z * w.w;
            }
            {
                const float4 w = ((const float4*)(Wh + (size_t)(r + 3) * 1024))[j];
                acc.x += a4.w * w.x; acc.y += a4.w * w.y; acc.z += a4.w * w.z; acc.w += a4.w * w.w;
            }
        }
        // prefetch next Z row (issued before barrier B, consumed next iter)
        if (Z && kq == 0 && t + 1 < SS)
            zr = ((const float4*)(Z + (size_t)((t + 1) * BB + b) * 1024))[j];
        ((float4*)psum[kq])[j] = acc;
        __syncthreads();                        // B: psum complete, hsh reads done
        if (tid < HH) {
            const float zi = psum[0][j]        + psum[1][j]        + psum[2][j]        + psum[3][j];
            const float zg = psum[0][256 + j]  + psum[1][256 + j]  + psum[2][256 + j]  + psum[3][256 + j];
            const float zf = psum[0][512 + j]  + psum[1][512 + j]  + psum[2][512 + j]  + psum[3][512 + j];
            const float zo = psum[0][768 + j]  + psum[1][768 + j]  + psum[2][768 + j]  + psum[3][768 + j];
            const float ig = sigmoidf_(zi);
            const float gg = tanhf(zg);
            const float fg = sigmoidf_(zf + 1.0f);
            const float og = sigmoidf_(zo);
            const float cn = fg * c + ig * gg;
            const float hn = og * tanhf(cn);
            const bool act = (t < len);
            c = act ? cn : c;
            const float ho = act ? hn : hprev;
            hprev = ho;
            outp[(size_t)(t * BB + b) * HH + j] = act ? hn : 0.f;
            hsh[j] = ho;                        // visible after next A
        }
    }
}

// Fused projection + online-softmax partials, flash-style over a V-chunk.
// Block: 32 rows x one V-chunk; 256 threads = 16 tx (4 cols) x 16 ty (2 rows).
// Emits per-(row,chunk) partial (m, l, tgt) to workspace.
__global__ __launch_bounds__(256, 4)
void ce_kernel(const float* __restrict__ h2, const float* __restrict__ W,
               const float* __restrict__ ob, const int* __restrict__ y,
               float* __restrict__ pm, float* __restrict__ pl, float* __restrict__ pt)
{
    __shared__ float sh[32][257];
    const int tid = threadIdx.x;
    const int tx = tid & 15, ty = tid >> 4;
    const int m0 = blockIdx.x * 32;
    const int cb = blockIdx.y;
    const int cstart = cb * CCHUNK;
    const int cend = (cstart + CCHUNK < VV) ? (cstart + CCHUNK) : VV;
    for (int i = tid; i < 32 * 64; i += 256) {
        const int r = i >> 6, c4 = i & 63;
        const float4 v = ((const float4*)(h2 + (size_t)(m0 + r) * HH))[c4];
        sh[r][c4 * 4 + 0] = v.x; sh[r][c4 * 4 + 1] = v.y;
        sh[r][c4 * 4 + 2] = v.z; sh[r][c4 * 4 + 3] = v.w;
    }
    __syncthreads();
    float mrun[2], lrun[2], tgt[2];
    int yv[2];
#pragma unroll
    for (int i = 0; i < 2; i++) {
        const int m = m0 + ty * 2 + i;
        const int s = m >> 5, b = m & (BB - 1);
        yv[i] = y[b * SS + s];
        mrun[i] = -INFINITY; lrun[i] = 0.f; tgt[i] = 0.f;
    }
    for (int c0 = cstart; c0 < cend; c0 += 64) {
        const int cc = c0 + tx * 4;
        float4 acc[2];
#pragma unroll
        for (int i = 0; i < 2; i++) acc[i] = make_float4(0.f, 0.f, 0.f, 0.f);
        if (c0 + 64 <= cend) {
            for (int k = 0; k < HH; k++) {
                const float4 w = *(const float4*)(W + (size_t)k * VV + cc);
#pragma unroll
                for (int i = 0; i < 2; i++) {
                    const float a = sh[ty * 2 + i][k];
                    acc[i].x += a * w.x; acc[i].y += a * w.y;
                    acc[i].z += a * w.z; acc[i].w += a * w.w;
                }
            }
        } else {
            for (int k = 0; k < HH; k++) {
                float4 w;
                w.x = (cc + 0 < cend) ? W[(size_t)k * VV + cc + 0] : 0.f;
                w.y = (cc + 1 < cend) ? W[(size_t)k * VV + cc + 1] : 0.f;
                w.z = (cc + 2 < cend) ? W[(size_t)k * VV + cc + 2] : 0.f;
                w.w = (cc + 3 < cend) ? W[(size_t)k * VV + cc + 3] : 0.f;
#pragma unroll
                for (int i = 0; i < 2; i++) {
                    const float a = sh[ty * 2 + i][k];
                    acc[i].x += a * w.x; acc[i].y += a * w.y;
                    acc[i].z += a * w.z; acc[i].w += a * w.w;
                }
            }
        }
        float ob4[4];
#pragma unroll
        for (int jj = 0; jj < 4; jj++) ob4[jj] = (cc + jj < cend) ? ob[cc + jj] : 0.f;
#pragma unroll
        for (int i = 0; i < 2; i++) {
            float sc[4] = { acc[i].x + ob4[0], acc[i].y + ob4[1],
                            acc[i].z + ob4[2], acc[i].w + ob4[3] };
#pragma unroll
            for (int jj = 0; jj < 4; jj++) if (cc + jj >= cend) sc[jj] = -INFINITY;
#pragma unroll
            for (int jj = 0; jj < 4; jj++)
                if ((cc + jj == yv[i]) && (cc + jj < cend)) tgt[i] += sc[jj];
            float cm = fmaxf(fmaxf(sc[0], sc[1]), fmaxf(sc[2], sc[3]));
            for (int off = 1; off < 16; off <<= 1) cm = fmaxf(cm, __shfl_xor(cm, off, 16));
            const float newm = fmaxf(mrun[i], cm);
            float ssum = 0.f;
#pragma unroll
            for (int jj = 0; jj < 4; jj++) ssum += expf(sc[jj] - newm);
            for (int off = 1; off < 16; off <<= 1) ssum += __shfl_xor(ssum, off, 16);
            lrun[i] = lrun[i] * expf(mrun[i] - newm) + ssum;
            mrun[i] = newm;
        }
    }
#pragma unroll
    for (int i = 0; i < 2; i++) {
        for (int off = 1; off < 16; off <<= 1) tgt[i] += __shfl_xor(tgt[i], off, 16);
        if (tx == 0) {
            const int m = m0 + ty * 2 + i;
            pm[(size_t)m * NC + cb] = mrun[i];
            pl[(size_t)m * NC + cb] = lrun[i];
            pt[(size_t)m * NC + cb] = tgt[i];
        }
    }
}

// Merge V-chunk partials -> per-row xent -> masked, length-normalized mean.
__global__ __launch_bounds__(256)
void fin_kernel(const float* __restrict__ pm, const float* __restrict__ pl,
                const float* __restrict__ pt, const int* __restrict__ y,
                const int* __restrict__ lens, float* __restrict__ out)
{
    __shared__ float red[4];
    const int m = blockIdx.x * 256 + threadIdx.x;
    const int s = m >> 5, b = m & (BB - 1);
    const int yv = y[b * SS + s];
    const float m0 = pm[(size_t)m * NC + 0], m1 = pm[(size_t)m * NC + 1];
    const float mx = fmaxf(m0, m1);
    const float l = pl[(size_t)m * NC + 0] * expf(m0 - mx)
                  + pl[(size_t)m * NC + 1] * expf(m1 - mx);
    const float lse = mx + logf(l);
    const float tg = pt[(size_t)m * NC + 0] + pt[(size_t)m * NC + 1];
    float local = (yv != 0) ? (lse - tg) / (32.0f * (float)lens[b]) : 0.f;
    for (int off = 1; off < 64; off <<= 1) local += __shfl_xor(local, off);
    const int wv = threadIdx.x >> 6;
    if ((threadIdx.x & 63) == 0) red[wv] = local;
    __syncthreads();
    if (threadIdx.x == 0)
        atomicAdd(out, red[0] + red[1] + red[2] + red[3]);
}

extern "C" void kernel_launch(void* const* d_in, const int* in_sizes, int n_in,
                              void* d_out, int out_size, void* d_ws, size_t ws_size,
                              hipStream_t stream)
{
    const int*   input_x = (const int*)  d_in[0];
    const int*   input_y = (const int*)  d_in[1];
    const int*   lens    = (const int*)  d_in[2];
    const float* emb_W   = (const float*)d_in[3];
    const float* k0      = (const float*)d_in[4];
    const float* b0      = (const float*)d_in[5];
    const float* k1      = (const float*)d_in[6];
    const float* b1      = (const float*)d_in[7];
    const float* out_W   = (const float*)d_in[8];
    const float* out_b   = (const float*)d_in[9];
    float* out = (float*)d_out;

    const size_t zbytes = (size_t)NROWS * 1024 * sizeof(float); // 64 MB
    const size_t hbytes = (size_t)NROWS * HH * sizeof(float);   // 16 MB
    const size_t pbytes = (size_t)NROWS * NC * 3 * sizeof(float); // 384 KB
    const bool useZ = (ws_size >= zbytes + 2 * hbytes);         // 96 MB total

    float* Z  = (float*)d_ws;
    float* h1 = useZ ? (float*)((char*)d_ws + zbytes) : (float*)d_ws;
    float* h2 = (float*)((char*)h1 + hbytes);
    // partials alias h1 when useZ (h1 dead after zgemm of layer 1)
    float* pm = useZ ? h1 : (float*)((char*)h2 + hbytes);
    float* pl = pm + (size_t)NROWS * NC;
    float* pt = pl + (size_t)NROWS * NC;
    (void)pbytes;

    hipMemsetAsync(d_out, 0, sizeof(float), stream);

    if (useZ) {
        zgemm_kernel<<<NROWS / 16, 256, 0, stream>>>(k0, b0, emb_W, input_x, Z, EE);
        lstm_kernel <<<BB, 1024, 0, stream>>>(k0, b0, lens, nullptr, nullptr, Z, h1, EE);
        zgemm_kernel<<<NROWS / 16, 256, 0, stream>>>(k1, b1, h1, nullptr, Z, HH);
        lstm_kernel <<<BB, 1024, 0, stream>>>(k1, b1, lens, nullptr, nullptr, Z, h2, HH);
    } else {
        lstm_kernel <<<BB, 1024, 0, stream>>>(k0, b0, lens, input_x, emb_W, nullptr, h1, EE);
        lstm_kernel <<<BB, 1024, 0, stream>>>(k1, b1, lens, nullptr, h1, nullptr, h2, HH);
    }
    ce_kernel<<<dim3(NROWS / 32, NC), 256, 0, stream>>>(h2, out_W, out_b, input_y, pm, pl, pt);
    fin_kernel<<<NROWS / 256, 256, 0, stream>>>(pm, pl, pt, input_y, lens, out);
}

// Round 3
// 4637.270 us; speedup vs baseline: 2.6644x; 2.3576x over previous
//
#include <hip/hip_runtime.h>
#include <cmath>

#define SS 512
#define BB 32
#define EE 128
#define HH 256
#define VV 10000
#define NROWS (SS*BB)   // 16384
#define VPAD 10048      // 4 waves * 157 tiles * 16

typedef __attribute__((ext_vector_type(8))) short bf16x8;
typedef __attribute__((ext_vector_type(4))) float f32x4;

__device__ __forceinline__ float sigmoidf_(float x) { return 1.0f / (1.0f + expf(-x)); }

__device__ __forceinline__ unsigned short f2bf(float x) {
    unsigned u = __float_as_uint(x);
    u = (u + 0x7FFFu + ((u >> 16) & 1u)) >> 16;   // RNE
    return (unsigned short)u;
}

__device__ __forceinline__ void release_add(unsigned int* p) {
    __hip_atomic_fetch_add(p, 1u, __ATOMIC_RELEASE, __HIP_MEMORY_SCOPE_AGENT);
}
__device__ __forceinline__ void poll_flag(unsigned int* p, unsigned int target) {
    int it = 0;
    while (__hip_atomic_load(p, __ATOMIC_RELAXED, __HIP_MEMORY_SCOPE_AGENT) < target) {
        __builtin_amdgcn_s_sleep(1);
        if (++it > 100000000) break;   // anti-hang cap; never trips if logic is right
    }
    (void)__hip_atomic_load(p, __ATOMIC_ACQUIRE, __HIP_MEMORY_SCOPE_AGENT);
}

// ---------------- Z precompute for layer 1 (validated in R1/R2) ----------------
// Z[m][0:1024] = b0 + emb[x[m]] @ k0[0:128]
__global__ __launch_bounds__(256)
void zgemm_kernel(const float* __restrict__ Wk, const float* __restrict__ bias,
                  const float* __restrict__ xin, const int* __restrict__ idx,
                  float* __restrict__ Z, int Kx)
{
    __shared__ float A[16][256];
    const int tid = threadIdx.x;
    const int m0 = blockIdx.x * 16;
    for (int i = tid; i < 16 * EE; i += 256) {
        const int r = i >> 7, cc = i & (EE - 1);
        const int m = m0 + r;
        const int t = m >> 5, b = m & (BB - 1);
        const int id = idx[b * SS + t];
        A[r][cc] = xin[(size_t)id * EE + cc];
    }
    __syncthreads();
    const float4 b4 = ((const float4*)bias)[tid];
    float4 acc[16];
#pragma unroll
    for (int i = 0; i < 16; i++) acc[i] = b4;
    for (int r = 0; r < Kx; r++) {
        const float4 w = ((const float4*)(Wk + (size_t)r * 1024))[tid];
#pragma unroll
        for (int i = 0; i < 16; i++) {
            const float a = A[i][r];
            acc[i].x += a * w.x; acc[i].y += a * w.y;
            acc[i].z += a * w.z; acc[i].w += a * w.w;
        }
    }
#pragma unroll
    for (int i = 0; i < 16; i++)
        ((float4*)(Z + (size_t)(m0 + i) * 1024))[tid] = acc[i];
}

// ---------------- W -> Wt bf16 transpose ([256][10000] -> [10048][256]) -------
__global__ __launch_bounds__(256)
void wtrans_kernel(const float* __restrict__ W, unsigned short* __restrict__ Wt)
{
    __shared__ float tile[64][65];
    const int tid = threadIdx.x;
    const int n0 = blockIdx.x * 64, k0 = blockIdx.y * 64;
    for (int i = tid; i < 4096; i += 256) {
        const int kk = i >> 6, nn = i & 63;
        const int n = n0 + nn;
        tile[kk][nn] = (n < VV) ? W[(size_t)(k0 + kk) * VV + n] : 0.f;
    }
    __syncthreads();
    for (int i = tid; i < 4096; i += 256) {
        const int nn = i >> 6, kk = i & 63;
        Wt[(size_t)(n0 + nn) * 256 + k0 + kk] = f2bf(tile[kk][nn]);
    }
}

__global__ __launch_bounds__(256)
void obset_kernel(const float* __restrict__ ob, float* __restrict__ obp)
{
    const int v = blockIdx.x * 256 + threadIdx.x;
    if (v < VPAD) obp[v] = (v < VV) ? ob[v] : -INFINITY;
}

// ---------------- Fused 2-layer LSTM, unit-sliced, flag-synced ----------------
// Blocks 0..31: layer 1, 8 units each, weights (h-part) LDS-resident, x-part from Z.
// Blocks 32..95: layer 2, 4 units each, wh+wx LDS-resident, x from out1 per step.
// h-state exchanged via st1/st2 (2 slots) + release/acquire flags f1/f2.
__global__ __launch_bounds__(512)
void lstm2_kernel(const float* __restrict__ k0w, const float* __restrict__ k1w,
                  const float* __restrict__ b1v, const int* __restrict__ lens,
                  const float* __restrict__ Z, float* __restrict__ out1,
                  unsigned short* __restrict__ h2bf,
                  float* __restrict__ st1, float* __restrict__ st2,
                  unsigned int* __restrict__ f1, unsigned int* __restrict__ f2)
{
    __shared__ float wsh[8192];    // L1: wh[k][u8][g4]; L2: wh[k][u4][g4] + wx at +4096
    __shared__ float psum[2048];
    const int tid = threadIdx.x;

    if (blockIdx.x < 32) {
        // ---------------- layer 1 ----------------
        const int j0 = blockIdx.x * 8;
        for (int i = tid; i < 8192; i += 512) {
            const int k = i >> 5, u = (i >> 2) & 7, g = i & 3;
            wsh[i] = k0w[(size_t)(EE + k) * 1024 + g * 256 + j0 + u];
        }
        const int kq = tid >> 8;          // 0..1 (k-half)
        const int j  = tid & 255;
        const int b  = j >> 3;            // 0..31
        const int u  = j & 7;             // 0..7
        const int col = j0 + u;
        const bool gate = (tid < 256);
        const int len = lens[b];
        float c = 0.f, hprev = 0.f;
        const float4* wp4 = (const float4*)wsh;
        __syncthreads();

        for (int t = 0; t < SS; t++) {
            float z0 = 0.f, z1 = 0.f, z2 = 0.f, z3 = 0.f;
            if (gate) {                    // prefetch x-part (stable data) under poll
                const float* zp = Z + (size_t)(t * BB + b) * 1024 + col;
                z0 = zp[0]; z1 = zp[256]; z2 = zp[512]; z3 = zp[768];
            }
            if (t > 0 && tid == 0) poll_flag(&f1[t - 1], 32);
            __syncthreads();

            float ax = 0.f, ay = 0.f, az = 0.f, aw = 0.f;
            if (t > 0) {
                const int rslot = (t - 1) & 1;
                const float4* hp = (const float4*)(st1 + rslot * 8192 + (b << 8) + (kq << 7));
#pragma unroll 4
                for (int k4 = 0; k4 < 32; ++k4) {
                    const float4 h4 = hp[k4];
                    const int kk = (kq << 7) + (k4 << 2);
                    const float4 w0 = wp4[(kk + 0) * 8 + u];
                    const float4 w1 = wp4[(kk + 1) * 8 + u];
                    const float4 w2 = wp4[(kk + 2) * 8 + u];
                    const float4 w3 = wp4[(kk + 3) * 8 + u];
                    ax += h4.x * w0.x; ay += h4.x * w0.y; az += h4.x * w0.z; aw += h4.x * w0.w;
                    ax += h4.y * w1.x; ay += h4.y * w1.y; az += h4.y * w1.z; aw += h4.y * w1.w;
                    ax += h4.z * w2.x; ay += h4.z * w2.y; az += h4.z * w2.z; aw += h4.z * w2.w;
                    ax += h4.w * w3.x; ay += h4.w * w3.y; az += h4.w * w3.z; aw += h4.w * w3.w;
                }
            }
            ((float4*)psum)[(kq << 8) + j] = make_float4(ax, ay, az, aw);
            __syncthreads();

            if (gate) {
                const float4 p0 = ((const float4*)psum)[j];
                const float4 p1 = ((const float4*)psum)[256 + j];
                const float zi = p0.x + p1.x + z0;
                const float zg = p0.y + p1.y + z1;
                const float zf = p0.z + p1.z + z2;
                const float zo = p0.w + p1.w + z3;
                const float ig = sigmoidf_(zi);
                const float gg = tanhf(zg);
                const float fg = sigmoidf_(zf + 1.0f);
                const float og = sigmoidf_(zo);
                const float cn = fg * c + ig * gg;
                const float hn = og * tanhf(cn);
                const bool act = (t < len);
                c = act ? cn : c;
                const float ho = act ? hn : hprev;
                hprev = ho;
                st1[(t & 1) * 8192 + (b << 8) + col] = ho;
                out1[(size_t)t * 8192 + (b << 8) + col] = act ? hn : 0.f;
            }
            __syncthreads();               // drains all waves' stores (vmcnt(0) at barrier)
            if (tid == 0) release_add(&f1[t]);
        }
    } else {
        // ---------------- layer 2 ----------------
        const int blk2 = blockIdx.x - 32;
        const int j0 = blk2 * 4;
        for (int i = tid; i < 4096; i += 512) {
            const int k = i >> 4, u = (i >> 2) & 3, g = i & 3;
            wsh[i]        = k1w[(size_t)(HH + k) * 1024 + g * 256 + j0 + u];  // wh
            wsh[4096 + i] = k1w[(size_t)k        * 1024 + g * 256 + j0 + u]; // wx
        }
        const int kq = tid >> 7;          // 0..3 (k-quarter)
        const int j  = tid & 127;
        const int b  = j >> 2;            // 0..31
        const int u  = j & 3;             // 0..3
        const int col = j0 + u;
        const bool gate = (tid < 128);
        const int len = lens[b];
        float bz0 = 0.f, bz1 = 0.f, bz2 = 0.f, bz3 = 0.f;
        if (gate) {
            bz0 = b1v[0 * 256 + col]; bz1 = b1v[1 * 256 + col];
            bz2 = b1v[2 * 256 + col]; bz3 = b1v[3 * 256 + col];
        }
        float c = 0.f, hprev = 0.f;
        const float4* wh4 = (const float4*)wsh;
        const float4* wx4 = (const float4*)(wsh + 4096);
        __syncthreads();

        for (int t = 0; t < SS; t++) {
            if (tid == 0) {
                poll_flag(&f1[t], 32);                 // out1[t] ready
                if (t > 0) poll_flag(&f2[t - 1], 64);  // own state ready
            }
            __syncthreads();

            float ax = 0.f, ay = 0.f, az = 0.f, aw = 0.f;
            {   // x part: out1[t]
                const float4* xp = (const float4*)(out1 + (size_t)t * 8192 + (b << 8) + (kq << 6));
#pragma unroll 4
                for (int k4 = 0; k4 < 16; ++k4) {
                    const float4 h4 = xp[k4];
                    const int kk = (kq << 6) + (k4 << 2);
                    const float4 w0 = wx4[(kk + 0) * 4 + u];
                    const float4 w1 = wx4[(kk + 1) * 4 + u];
                    const float4 w2 = wx4[(kk + 2) * 4 + u];
                    const float4 w3 = wx4[(kk + 3) * 4 + u];
                    ax += h4.x * w0.x; ay += h4.x * w0.y; az += h4.x * w0.z; aw += h4.x * w0.w;
                    ax += h4.y * w1.x; ay += h4.y * w1.y; az += h4.y * w1.z; aw += h4.y * w1.w;
                    ax += h4.z * w2.x; ay += h4.z * w2.y; az += h4.z * w2.z; aw += h4.z * w2.w;
                    ax += h4.w * w3.x; ay += h4.w * w3.y; az += h4.w * w3.z; aw += h4.w * w3.w;
                }
            }
            if (t > 0) {
                const int rslot = (t - 1) & 1;
                const float4* hp = (const float4*)(st2 + rslot * 8192 + (b << 8) + (kq << 6));
#pragma unroll 4
                for (int k4 = 0; k4 < 16; ++k4) {
                    const float4 h4 = hp[k4];
                    const int kk = (kq << 6) + (k4 << 2);
                    const float4 w0 = wh4[(kk + 0) * 4 + u];
                    const float4 w1 = wh4[(kk + 1) * 4 + u];
                    const float4 w2 = wh4[(kk + 2) * 4 + u];
                    const float4 w3 = wh4[(kk + 3) * 4 + u];
                    ax += h4.x * w0.x; ay += h4.x * w0.y; az += h4.x * w0.z; aw += h4.x * w0.w;
                    ax += h4.y * w1.x; ay += h4.y * w1.y; az += h4.y * w1.z; aw += h4.y * w1.w;
                    ax += h4.z * w2.x; ay += h4.z * w2.y; az += h4.z * w2.z; aw += h4.z * w2.w;
                    ax += h4.w * w3.x; ay += h4.w * w3.y; az += h4.w * w3.z; aw += h4.w * w3.w;
                }
            }
            ((float4*)psum)[(kq << 7) + j] = make_float4(ax, ay, az, aw);
            __syncthreads();

            if (gate) {
                const float4 p0 = ((const float4*)psum)[j];
                const float4 p1 = ((const float4*)psum)[128 + j];
                const float4 p2 = ((const float4*)psum)[256 + j];
                const float4 p3 = ((const float4*)psum)[384 + j];
                const float zi = p0.x + p1.x + p2.x + p3.x + bz0;
                const float zg = p0.y + p1.y + p2.y + p3.y + bz1;
                const float zf = p0.z + p1.z + p2.z + p3.z + bz2;
                const float zo = p0.w + p1.w + p2.w + p3.w + bz3;
                const float ig = sigmoidf_(zi);
                const float gg = tanhf(zg);
                const float fg = sigmoidf_(zf + 1.0f);
                const float og = sigmoidf_(zo);
                const float cn = fg * c + ig * gg;
                const float hn = og * tanhf(cn);
                const bool act = (t < len);
                c = act ? cn : c;
                const float ho = act ? hn : hprev;
                hprev = ho;
                st2[(t & 1) * 8192 + (b << 8) + col] = ho;
                h2bf[(size_t)t * 8192 + (b << 8) + col] = f2bf(act ? hn : 0.f);
            }
            __syncthreads();
            if (tid == 0) release_add(&f2[t]);
        }
    }
}

// ---------------- MFMA bf16 fused projection + CE ----------------
// Block: 64 rows, 256 threads = 4 waves. Wave w sweeps V-chunk [w*2512, +2512).
// A-frags (4 m-tiles x 8 k-frags) register-resident; fixed-max (16) softmax.
__global__ __launch_bounds__(256, 1)
void ce_kernel(const unsigned short* __restrict__ h2bf,
               const unsigned short* __restrict__ Wt,
               const float* __restrict__ obp, const int* __restrict__ y,
               const int* __restrict__ lens, float* __restrict__ out)
{
    __shared__ unsigned short h2t[64 * 264];
    __shared__ float lsw[4][64];
    __shared__ float tgt64[64];
    const int tid = threadIdx.x;
    const int w = tid >> 6, lane = tid & 63;
    const int q = lane >> 4, n16 = lane & 15;
    const int m0 = blockIdx.x * 64;

    for (int i = tid; i < 64 * 32; i += 256) {       // stage 64x256 bf16 rows
        const int r = i >> 5, s = i & 31;
        *(uint4*)&h2t[r * 264 + s * 8] = *(const uint4*)(h2bf + (size_t)(m0 + r) * 256 + s * 8);
    }
    if (tid < 64) tgt64[tid] = 0.f;
    __syncthreads();

    bf16x8 A[4][8];
#pragma unroll
    for (int mt = 0; mt < 4; mt++) {
        const int row = mt * 16 + n16;
#pragma unroll
        for (int kb = 0; kb < 8; kb++)
            A[mt][kb] = *(const bf16x8*)&h2t[row * 264 + kb * 32 + q * 8];
    }
    int yv[16];
#pragma unroll
    for (int mt = 0; mt < 4; mt++)
#pragma unroll
        for (int r = 0; r < 4; r++) {
            const int m = m0 + mt * 16 + q * 4 + r;
            yv[mt * 4 + r] = y[(m & 31) * SS + (m >> 5)];
        }
    float lsum[16];
#pragma unroll
    for (int i = 0; i < 16; i++) lsum[i] = 0.f;

    const int cbase = w * 2512;
    for (int tile = 0; tile < 157; tile++) {
        const int n = cbase + tile * 16 + n16;
        const unsigned short* bp = Wt + (size_t)n * 256 + q * 8;
        bf16x8 B[8];
#pragma unroll
        for (int kb = 0; kb < 8; kb++) B[kb] = *(const bf16x8*)(bp + kb * 32);
        const float obv = obp[n];
        f32x4 C[4];
#pragma unroll
        for (int mt = 0; mt < 4; mt++) {
            C[mt] = (f32x4){0.f, 0.f, 0.f, 0.f};
#pragma unroll
            for (int kb = 0; kb < 8; kb++)
                C[mt] = __builtin_amdgcn_mfma_f32_16x16x32_bf16(A[mt][kb], B[kb], C[mt], 0, 0, 0);
        }
#pragma unroll
        for (int mt = 0; mt < 4; mt++)
#pragma unroll
            for (int r = 0; r < 4; r++) {
                const float sc = C[mt][r] + obv;     // -inf for padded cols
                if (n == yv[mt * 4 + r]) tgt64[mt * 16 + q * 4 + r] = sc;
                lsum[mt * 4 + r] += __expf(sc - 16.0f);
            }
    }
#pragma unroll
    for (int i = 0; i < 16; i++) {
        float v = lsum[i];
        v += __shfl_xor(v, 1, 16); v += __shfl_xor(v, 2, 16);
        v += __shfl_xor(v, 4, 16); v += __shfl_xor(v, 8, 16);
        lsum[i] = v;
    }
    if (n16 == 0)
#pragma unroll
        for (int i = 0; i < 16; i++)
            lsw[w][(i >> 2) * 16 + q * 4 + (i & 3)] = lsum[i];
    __syncthreads();

    if (tid < 64) {
        const float l = lsw[0][tid] + lsw[1][tid] + lsw[2][tid] + lsw[3][tid];
        const float lse = 16.0f + __logf(l);
        const int m = m0 + tid;
        const int tt = m >> 5, bb = m & 31;
        const int yvv = y[bb * SS + tt];
        float local = (yvv != 0) ? (lse - tgt64[tid]) / (32.0f * (float)lens[bb]) : 0.f;
        for (int off = 1; off < 64; off <<= 1) local += __shfl_xor(local, off, 64);
        if (tid == 0) atomicAdd(out, local);
    }
}

extern "C" void kernel_launch(void* const* d_in, const int* in_sizes, int n_in,
                              void* d_out, int out_size, void* d_ws, size_t ws_size,
                              hipStream_t stream)
{
    const int*   input_x = (const int*)  d_in[0];
    const int*   input_y = (const int*)  d_in[1];
    const int*   lens    = (const int*)  d_in[2];
    const float* emb_W   = (const float*)d_in[3];
    const float* k0      = (const float*)d_in[4];
    const float* b0      = (const float*)d_in[5];
    const float* k1      = (const float*)d_in[6];
    const float* b1      = (const float*)d_in[7];
    const float* out_W   = (const float*)d_in[8];
    const float* out_b   = (const float*)d_in[9];
    float* out = (float*)d_out;

    char* p = (char*)d_ws;
    float* Z = (float*)p;                 p += (size_t)NROWS * 1024 * 4;   // 67.1 MB
    float* out1 = (float*)p;              p += (size_t)SS * 32 * 256 * 4;  // 16.8 MB
    unsigned short* h2bf = (unsigned short*)p; p += (size_t)SS * 32 * 256 * 2; // 8.4 MB
    unsigned short* Wt = (unsigned short*)p;   p += (size_t)VPAD * 256 * 2;    // 5.1 MB
    float* obp = (float*)p;               p += (size_t)VPAD * 4;
    float* st1 = (float*)p;               p += 2 * 8192 * 4;
    float* st2 = (float*)p;               p += 2 * 8192 * 4;
    unsigned int* f1 = (unsigned int*)p;  p += 512 * 4;
    unsigned int* f2 = (unsigned int*)p;  p += 512 * 4;

    hipMemsetAsync(d_out, 0, sizeof(float), stream);
    hipMemsetAsync(f1, 0, 2 * 512 * 4, stream);

    zgemm_kernel<<<NROWS / 16, 256, 0, stream>>>(k0, b0, emb_W, input_x, Z, EE);
    wtrans_kernel<<<dim3(VPAD / 64, 4), 256, 0, stream>>>(out_W, Wt);
    obset_kernel<<<(VPAD + 255) / 256, 256, 0, stream>>>(out_b, obp);
    lstm2_kernel<<<96, 512, 0, stream>>>(k0, k1, b1, lens, Z, out1, h2bf, st1, st2, f1, f2);
    ce_kernel<<<NROWS / 64, 256, 0, stream>>>(h2bf, Wt, obp, input_y, lens, out);
}

// Round 5
// 3840.003 us; speedup vs baseline: 3.2176x; 1.2076x over previous
//
#include <hip/hip_runtime.h>
#include <cmath>

#define SS 512
#define BB 32
#define EE 128
#define HH 256
#define VV 10000
#define NROWS (SS*BB)   // 16384
#define VPAD 10048      // 4 waves * 157 tiles * 16
#define NB1 16
#define NB2 16

typedef __attribute__((ext_vector_type(8))) short bf16x8;
typedef __attribute__((ext_vector_type(4))) float f32x4;

__device__ __forceinline__ float sigmoidf_(float x) { return 1.0f / (1.0f + expf(-x)); }

__device__ __forceinline__ unsigned short f2bf(float x) {
    unsigned u = __float_as_uint(x);
    u = (u + 0x7FFFu + ((u >> 16) & 1u)) >> 16;   // RNE
    return (unsigned short)u;
}

// ---------------- Z precompute for layer 1 (validated R1-R3) ----------------
__global__ __launch_bounds__(256)
void zgemm_kernel(const float* __restrict__ Wk, const float* __restrict__ bias,
                  const float* __restrict__ xin, const int* __restrict__ idx,
                  float* __restrict__ Z, int Kx)
{
    __shared__ float A[16][256];
    const int tid = threadIdx.x;
    const int m0 = blockIdx.x * 16;
    for (int i = tid; i < 16 * EE; i += 256) {
        const int r = i >> 7, cc = i & (EE - 1);
        const int m = m0 + r;
        const int t = m >> 5, b = m & (BB - 1);
        const int id = idx[b * SS + t];
        A[r][cc] = xin[(size_t)id * EE + cc];
    }
    __syncthreads();
    const float4 b4 = ((const float4*)bias)[tid];
    float4 acc[16];
#pragma unroll
    for (int i = 0; i < 16; i++) acc[i] = b4;
    for (int r = 0; r < Kx; r++) {
        const float4 w = ((const float4*)(Wk + (size_t)r * 1024))[tid];
#pragma unroll
        for (int i = 0; i < 16; i++) {
            const float a = A[i][r];
            acc[i].x += a * w.x; acc[i].y += a * w.y;
            acc[i].z += a * w.z; acc[i].w += a * w.w;
        }
    }
#pragma unroll
    for (int i = 0; i < 16; i++)
        ((float4*)(Z + (size_t)(m0 + i) * 1024))[tid] = acc[i];
}

// ---------------- W -> Wt bf16 transpose (validated R3) ----------------
__global__ __launch_bounds__(256)
void wtrans_kernel(const float* __restrict__ W, unsigned short* __restrict__ Wt)
{
    __shared__ float tile[64][65];
    const int tid = threadIdx.x;
    const int n0 = blockIdx.x * 64, k0 = blockIdx.y * 64;
    for (int i = tid; i < 4096; i += 256) {
        const int kk = i >> 6, nn = i & 63;
        const int n = n0 + nn;
        tile[kk][nn] = (n < VV) ? W[(size_t)(k0 + kk) * VV + n] : 0.f;
    }
    __syncthreads();
    for (int i = tid; i < 4096; i += 256) {
        const int nn = i >> 6, kk = i & 63;
        Wt[(size_t)(n0 + nn) * 256 + k0 + kk] = f2bf(tile[kk][nn]);
    }
}

__global__ __launch_bounds__(256)
void obset_kernel(const float* __restrict__ ob, float* __restrict__ obp)
{
    const int v = blockIdx.x * 256 + threadIdx.x;
    if (v < VPAD) obp[v] = (v < VV) ? ob[v] : -INFINITY;
}

// ---------------- Fused 2-layer LSTM: MFMA recurrence, per-block flags --------
// Blocks 0..15: layer 1 (16 units each). Blocks 16..31: layer 2.
// Gate-aligned n-tiles: tile g = gate g of the block's 16 units, so i/g/f/o of a
// (b,u) land in the same lane&register of C (C: col=lane&15=unit, row=q*4+r=batch).
// Weight B-frags are VGPR-resident for the whole sequence.
// h exchange: bf16 slots st1/st2 (double-buffered) + per-block release flags.
// Slot-overwrite safety: writer of slot t&1 (step t) first polls all flags of
// step t-1; a block sets flag t-1 only after its staging reads of slot t&1
// (= slot (t-2)&1) completed. Same invariant R3 ran bit-exact.
__global__ __launch_bounds__(256, 1)
void lstm2_kernel(const float* __restrict__ k0w, const float* __restrict__ k1w,
                  const float* __restrict__ b1v, const int* __restrict__ lens,
                  const float* __restrict__ Z,
                  unsigned short* __restrict__ out1, unsigned short* __restrict__ h2bf,
                  unsigned short* __restrict__ st1, unsigned short* __restrict__ st2,
                  unsigned int* __restrict__ f1, unsigned int* __restrict__ f2)
{
    __shared__ unsigned short hA[32 * 264];   // staged h, A-frag friendly, padded
    __shared__ unsigned short xA[32 * 264];   // staged x (layer 2 only)
    __shared__ float psX[2 * 4 * 64 * 4];     // layer-2 x-part partials
    const int tid = threadIdx.x;
    const int wid = tid >> 6, lane = tid & 63;
    const int q = lane >> 4, n16 = lane & 15;
    const int blk = blockIdx.x;

    if (blk < NB1) {
        // ================= layer 1 =================
        const int U0 = blk * 16;
        const int col = U0 + n16;
        const int m = wid;                    // m-tile for compute waves (wid<2)
        bf16x8 Bw[4][8];
        float c4[4] = {0.f, 0.f, 0.f, 0.f}, ho[4] = {0.f, 0.f, 0.f, 0.f};
        int len4[4] = {0, 0, 0, 0};
        if (wid < 2) {
#pragma unroll
            for (int g = 0; g < 4; g++)
#pragma unroll
                for (int kb = 0; kb < 8; kb++) {
                    bf16x8 fr;
#pragma unroll
                    for (int j = 0; j < 8; j++) {
                        const int k = kb * 32 + q * 8 + j;
                        fr[j] = (short)f2bf(k0w[(size_t)(EE + k) * 1024 + g * 256 + col]);
                    }
                    Bw[g][kb] = fr;
                }
#pragma unroll
            for (int r = 0; r < 4; r++) len4[r] = lens[m * 16 + q * 4 + r];
        }

        for (int t = 0; t < SS; t++) {
            float zx[4][4];
            if (wid < 2) {                    // x-part from Z (static data; issue early)
#pragma unroll
                for (int g = 0; g < 4; g++)
#pragma unroll
                    for (int r = 0; r < 4; r++)
                        zx[g][r] = Z[(size_t)(t * BB + m * 16 + q * 4 + r) * 1024 + g * 256 + col];
            }
            if (t > 0) {
                if (tid < NB1) {
                    int it = 0;
                    while (__hip_atomic_load(&f1[(t - 1) * NB1 + tid], __ATOMIC_RELAXED,
                                             __HIP_MEMORY_SCOPE_AGENT) == 0u) {
                        __builtin_amdgcn_s_sleep(1);
                        if (++it > 100000000) break;
                    }
                }
                __syncthreads();
                __builtin_amdgcn_fence(__ATOMIC_ACQUIRE, "agent");
                // stage st1 slot (t-1)&1 -> hA : 32 rows x 256 bf16 = 1024 uint4
                for (int i = tid; i < 1024; i += 256) {
                    const int r_ = i >> 5, s_ = i & 31;
                    *(uint4*)&hA[r_ * 264 + s_ * 8] =
                        *(const uint4*)(st1 + ((t - 1) & 1) * 8192 + r_ * 256 + s_ * 8);
                }
                __syncthreads();
            }
            if (wid < 2) {
                f32x4 C[4] = {{0,0,0,0},{0,0,0,0},{0,0,0,0},{0,0,0,0}};
                if (t > 0) {
                    bf16x8 A[8];
#pragma unroll
                    for (int kb = 0; kb < 8; kb++)
                        A[kb] = *(const bf16x8*)&hA[(m * 16 + n16) * 264 + kb * 32 + q * 8];
#pragma unroll
                    for (int g = 0; g < 4; g++)
#pragma unroll
                        for (int kb = 0; kb < 8; kb++)
                            C[g] = __builtin_amdgcn_mfma_f32_16x16x32_bf16(A[kb], Bw[g][kb], C[g], 0, 0, 0);
                }
                unsigned short hosh[4], outsh[4];
#pragma unroll
                for (int r = 0; r < 4; r++) {
                    const float zi = C[0][r] + zx[0][r];
                    const float zg = C[1][r] + zx[1][r];
                    const float zf = C[2][r] + zx[2][r];
                    const float zo = C[3][r] + zx[3][r];
                    const float ig = sigmoidf_(zi);
                    const float gg = tanhf(zg);
                    const float fg = sigmoidf_(zf + 1.0f);
                    const float og = sigmoidf_(zo);
                    const float cn = fg * c4[r] + ig * gg;
                    const float hn = og * tanhf(cn);
                    const bool act = (t < len4[r]);
                    c4[r] = act ? cn : c4[r];
                    ho[r] = act ? hn : ho[r];
                    hosh[r] = f2bf(ho[r]);
                    outsh[r] = f2bf(act ? hn : 0.f);
                }
#pragma unroll
                for (int r = 0; r < 4; r++) {
                    const int b = m * 16 + q * 4 + r;
                    st1[(t & 1) * 8192 + b * 256 + col] = hosh[r];
                    out1[(size_t)t * 8192 + b * 256 + col] = outsh[r];
                }
            }
            __syncthreads();   // waves drain vmcnt(0) before barrier -> stores in L2
            if (tid == 0)
                __hip_atomic_store(&f1[t * NB1 + blk], 1u, __ATOMIC_RELEASE,
                                   __HIP_MEMORY_SCOPE_AGENT);
        }
    } else {
        // ================= layer 2 =================
        const int blk2 = blk - NB1;
        const int U0 = blk2 * 16;
        const int col = U0 + n16;
        const int m = wid & 1;                // waves 0,1: h-part m; waves 2,3: x-part m
        const bool hwave = (wid < 2);
        const int koff = hwave ? HH : 0;      // h-rows vs x-rows of k1
        bf16x8 Bw[4][8];
#pragma unroll
        for (int g = 0; g < 4; g++)
#pragma unroll
            for (int kb = 0; kb < 8; kb++) {
                bf16x8 fr;
#pragma unroll
                for (int j = 0; j < 8; j++) {
                    const int k = kb * 32 + q * 8 + j;
                    fr[j] = (short)f2bf(k1w[(size_t)(koff + k) * 1024 + g * 256 + col]);
                }
                Bw[g][kb] = fr;
            }
        float c4[4] = {0.f, 0.f, 0.f, 0.f}, ho[4] = {0.f, 0.f, 0.f, 0.f};
        float bz[4] = {0.f, 0.f, 0.f, 0.f};
        int len4[4] = {0, 0, 0, 0};
        if (hwave) {
#pragma unroll
            for (int g = 0; g < 4; g++) bz[g] = b1v[g * 256 + col];
#pragma unroll
            for (int r = 0; r < 4; r++) len4[r] = lens[m * 16 + q * 4 + r];
        }

        for (int t = 0; t < SS; t++) {
            if (tid < NB1) {
                int it = 0;
                while (__hip_atomic_load(&f1[t * NB1 + tid], __ATOMIC_RELAXED,
                                         __HIP_MEMORY_SCOPE_AGENT) == 0u) {
                    __builtin_amdgcn_s_sleep(1);
                    if (++it > 100000000) break;
                }
            } else if (tid < NB1 + NB2 && t > 0) {
                int it = 0;
                while (__hip_atomic_load(&f2[(t - 1) * NB2 + (tid - NB1)], __ATOMIC_RELAXED,
                                         __HIP_MEMORY_SCOPE_AGENT) == 0u) {
                    __builtin_amdgcn_s_sleep(1);
                    if (++it > 100000000) break;
                }
            }
            __syncthreads();
            __builtin_amdgcn_fence(__ATOMIC_ACQUIRE, "agent");
            // stage out1[t] -> xA and st2 slot (t-1)&1 -> hA (1024 uint4 each)
            for (int i = tid; i < 1024; i += 256) {
                const int r_ = i >> 5, s_ = i & 31;
                *(uint4*)&xA[r_ * 264 + s_ * 8] =
                    *(const uint4*)(out1 + (size_t)t * 8192 + r_ * 256 + s_ * 8);
                if (t > 0)
                    *(uint4*)&hA[r_ * 264 + s_ * 8] =
                        *(const uint4*)(st2 + ((t - 1) & 1) * 8192 + r_ * 256 + s_ * 8);
            }
            __syncthreads();
            f32x4 C[4] = {{0,0,0,0},{0,0,0,0},{0,0,0,0},{0,0,0,0}};
            if (hwave) {
                if (t > 0) {
                    bf16x8 A[8];
#pragma unroll
                    for (int kb = 0; kb < 8; kb++)
                        A[kb] = *(const bf16x8*)&hA[(m * 16 + n16) * 264 + kb * 32 + q * 8];
#pragma unroll
                    for (int g = 0; g < 4; g++)
#pragma unroll
                        for (int kb = 0; kb < 8; kb++)
                            C[g] = __builtin_amdgcn_mfma_f32_16x16x32_bf16(A[kb], Bw[g][kb], C[g], 0, 0, 0);
                }
            } else {
                bf16x8 A[8];
#pragma unroll
                for (int kb = 0; kb < 8; kb++)
                    A[kb] = *(const bf16x8*)&xA[(m * 16 + n16) * 264 + kb * 32 + q * 8];
#pragma unroll
                for (int g = 0; g < 4; g++)
#pragma unroll
                    for (int kb = 0; kb < 8; kb++)
                        C[g] = __builtin_amdgcn_mfma_f32_16x16x32_bf16(A[kb], Bw[g][kb], C[g], 0, 0, 0);
#pragma unroll
                for (int g = 0; g < 4; g++)
                    *(f32x4*)&psX[((m * 4 + g) * 64 + lane) * 4] = C[g];
            }
            __syncthreads();
            if (hwave) {
                f32x4 Cx[4];
#pragma unroll
                for (int g = 0; g < 4; g++)
                    Cx[g] = *(const f32x4*)&psX[((m * 4 + g) * 64 + lane) * 4];
                unsigned short hosh[4], outsh[4];
#pragma unroll
                for (int r = 0; r < 4; r++) {
                    const float zi = C[0][r] + Cx[0][r] + bz[0];
                    const float zg = C[1][r] + Cx[1][r] + bz[1];
                    const float zf = C[2][r] + Cx[2][r] + bz[2];
                    const float zo = C[3][r] + Cx[3][r] + bz[3];
                    const float ig = sigmoidf_(zi);
                    const float gg = tanhf(zg);
                    const float fg = sigmoidf_(zf + 1.0f);
                    const float og = sigmoidf_(zo);
                    const float cn = fg * c4[r] + ig * gg;
                    const float hn = og * tanhf(cn);
                    const bool act = (t < len4[r]);
                    c4[r] = act ? cn : c4[r];
                    ho[r] = act ? hn : ho[r];
                    hosh[r] = f2bf(ho[r]);
                    outsh[r] = f2bf(act ? hn : 0.f);
                }
#pragma unroll
                for (int r = 0; r < 4; r++) {
                    const int b = m * 16 + q * 4 + r;
                    st2[(t & 1) * 8192 + b * 256 + col] = hosh[r];
                    h2bf[(size_t)t * 8192 + b * 256 + col] = outsh[r];
                }
            }
            __syncthreads();
            if (tid == 0)
                __hip_atomic_store(&f2[t * NB2 + blk2], 1u, __ATOMIC_RELEASE,
                                   __HIP_MEMORY_SCOPE_AGENT);
        }
    }
}

// ---------------- MFMA bf16 fused projection + CE (validated R3) ----------------
__global__ __launch_bounds__(256, 1)
void ce_kernel(const unsigned short* __restrict__ h2bf,
               const unsigned short* __restrict__ Wt,
               const float* __restrict__ obp, const int* __restrict__ y,
               const int* __restrict__ lens, float* __restrict__ out)
{
    __shared__ unsigned short h2t[64 * 264];
    __shared__ float lsw[4][64];
    __shared__ float tgt64[64];
    const int tid = threadIdx.x;
    const int w = tid >> 6, lane = tid & 63;
    const int q = lane >> 4, n16 = lane & 15;
    const int m0 = blockIdx.x * 64;

    for (int i = tid; i < 64 * 32; i += 256) {
        const int r = i >> 5, s = i & 31;
        *(uint4*)&h2t[r * 264 + s * 8] = *(const uint4*)(h2bf + (size_t)(m0 + r) * 256 + s * 8);
    }
    if (tid < 64) tgt64[tid] = 0.f;
    __syncthreads();

    bf16x8 A[4][8];
#pragma unroll
    for (int mt = 0; mt < 4; mt++) {
        const int row = mt * 16 + n16;
#pragma unroll
        for (int kb = 0; kb < 8; kb++)
            A[mt][kb] = *(const bf16x8*)&h2t[row * 264 + kb * 32 + q * 8];
    }
    int yv[16];
#pragma unroll
    for (int mt = 0; mt < 4; mt++)
#pragma unroll
        for (int r = 0; r < 4; r++) {
            const int m = m0 + mt * 16 + q * 4 + r;
            yv[mt * 4 + r] = y[(m & 31) * SS + (m >> 5)];
        }
    float lsum[16];
#pragma unroll
    for (int i = 0; i < 16; i++) lsum[i] = 0.f;

    const int cbase = w * 2512;
    for (int tile = 0; tile < 157; tile++) {
        const int n = cbase + tile * 16 + n16;
        const unsigned short* bp = Wt + (size_t)n * 256 + q * 8;
        bf16x8 B[8];
#pragma unroll
        for (int kb = 0; kb < 8; kb++) B[kb] = *(const bf16x8*)(bp + kb * 32);
        const float obv = obp[n];
        f32x4 C[4];
#pragma unroll
        for (int mt = 0; mt < 4; mt++) {
            C[mt] = (f32x4){0.f, 0.f, 0.f, 0.f};
#pragma unroll
            for (int kb = 0; kb < 8; kb++)
                C[mt] = __builtin_amdgcn_mfma_f32_16x16x32_bf16(A[mt][kb], B[kb], C[mt], 0, 0, 0);
        }
#pragma unroll
        for (int mt = 0; mt < 4; mt++)
#pragma unroll
            for (int r = 0; r < 4; r++) {
                const float sc = C[mt][r] + obv;     // -inf for padded cols
                if (n == yv[mt * 4 + r]) tgt64[mt * 16 + q * 4 + r] = sc;
                lsum[mt * 4 + r] += __expf(sc - 16.0f);
            }
    }
#pragma unroll
    for (int i = 0; i < 16; i++) {
        float v = lsum[i];
        v += __shfl_xor(v, 1, 16); v += __shfl_xor(v, 2, 16);
        v += __shfl_xor(v, 4, 16); v += __shfl_xor(v, 8, 16);
        lsum[i] = v;
    }
    if (n16 == 0)
#pragma unroll
        for (int i = 0; i < 16; i++)
            lsw[w][(i >> 2) * 16 + q * 4 + (i & 3)] = lsum[i];
    __syncthreads();

    if (tid < 64) {
        const float l = lsw[0][tid] + lsw[1][tid] + lsw[2][tid] + lsw[3][tid];
        const float lse = 16.0f + __logf(l);
        const int m = m0 + tid;
        const int tt = m >> 5, bb = m & 31;
        const int yvv = y[bb * SS + tt];
        float local = (yvv != 0) ? (lse - tgt64[tid]) / (32.0f * (float)lens[bb]) : 0.f;
        for (int off = 1; off < 64; off <<= 1) local += __shfl_xor(local, off, 64);
        if (tid == 0) atomicAdd(out, local);
    }
}

extern "C" void kernel_launch(void* const* d_in, const int* in_sizes, int n_in,
                              void* d_out, int out_size, void* d_ws, size_t ws_size,
                              hipStream_t stream)
{
    const int*   input_x = (const int*)  d_in[0];
    const int*   input_y = (const int*)  d_in[1];
    const int*   lens    = (const int*)  d_in[2];
    const float* emb_W   = (const float*)d_in[3];
    const float* k0      = (const float*)d_in[4];
    const float* b0      = (const float*)d_in[5];
    const float* k1      = (const float*)d_in[6];
    const float* b1      = (const float*)d_in[7];
    const float* out_W   = (const float*)d_in[8];
    const float* out_b   = (const float*)d_in[9];
    float* out = (float*)d_out;

    char* p = (char*)d_ws;
    float* Z = (float*)p;                       p += (size_t)NROWS * 1024 * 4;     // 67.1 MB
    unsigned short* out1 = (unsigned short*)p;  p += (size_t)NROWS * 256 * 2;      // 8.4 MB
    unsigned short* h2bf = (unsigned short*)p;  p += (size_t)NROWS * 256 * 2;      // 8.4 MB
    unsigned short* Wt = (unsigned short*)p;    p += (size_t)VPAD * 256 * 2;       // 5.1 MB
    float* obp = (float*)p;                     p += (size_t)VPAD * 4;
    unsigned short* st1 = (unsigned short*)p;   p += 2 * 8192 * 2;
    unsigned short* st2 = (unsigned short*)p;   p += 2 * 8192 * 2;
    unsigned int* f1 = (unsigned int*)p;        p += (size_t)SS * NB1 * 4;
    unsigned int* f2 = (unsigned int*)p;        p += (size_t)SS * NB2 * 4;

    hipMemsetAsync(d_out, 0, sizeof(float), stream);
    hipMemsetAsync(f1, 0, (size_t)SS * (NB1 + NB2) * 4, stream);

    zgemm_kernel<<<NROWS / 16, 256, 0, stream>>>(k0, b0, emb_W, input_x, Z, EE);
    wtrans_kernel<<<dim3(VPAD / 64, 4), 256, 0, stream>>>(out_W, Wt);
    obset_kernel<<<(VPAD + 255) / 256, 256, 0, stream>>>(out_b, obp);
    lstm2_kernel<<<NB1 + NB2, 256, 0, stream>>>(k0, k1, b1, lens, Z, out1, h2bf,
                                                st1, st2, f1, f2);
    ce_kernel<<<NROWS / 64, 256, 0, stream>>>(h2bf, Wt, obp, input_y, lens, out);
}